// Round 1
// baseline (2747.910 us; speedup 1.0000x reference)
//
#include <hip/hip_runtime.h>
#include <math.h>

#define DECAY 0.8f
constexpr int B_    = 16;
constexpr int NSEQ  = 4096;
constexpr int D     = 64;
constexpr int C     = 4096;
constexpr int N     = B_ * NSEQ;   // 65536 rows

// ---------------------------------------------------------------------------
// Kernel 1: embed_n = l2norm(embed); zero embed_sum and bins.
// One wave (64 lanes) per code; 4 codes per 256-thread block.
// ---------------------------------------------------------------------------
__global__ __launch_bounds__(256) void prep_kernel(
    const float* __restrict__ embed,
    float* __restrict__ embed_n,
    float* __restrict__ embed_sum,
    float* __restrict__ bins)
{
    int code = blockIdx.x * 4 + (threadIdx.x >> 6);
    int lane = threadIdx.x & 63;
    float v = embed[code * D + lane];
    float ss = v * v;
    #pragma unroll
    for (int o = 32; o > 0; o >>= 1) ss += __shfl_xor(ss, o);
    float inv = 1.0f / fmaxf(sqrtf(ss), 1e-12f);
    embed_n[code * D + lane]   = v * inv;
    embed_sum[code * D + lane] = 0.0f;
    if (lane == 0) bins[code] = 0.0f;
}

// ---------------------------------------------------------------------------
// Kernel 2: per x-row argmax over all codes + quantize gather + EMA scatters.
// One thread per row. Row held in 64 VGPRs. Codes processed 2 at a time with
// 4 independent accumulators each (ILP to hide FMA latency at 1 wave/SIMD).
// embed_n addresses are wave-uniform -> compiler should emit s_load; v_fmac
// then takes the code element as its one allowed SGPR operand.
// argmax is scale-invariant for positive row scale, so x is NOT normalized
// here; 1/||x|| is applied only in the embed_sum accumulation.
// ---------------------------------------------------------------------------
__global__ __launch_bounds__(256) void assign_kernel(
    const float* __restrict__ x,
    const float* __restrict__ embed,
    const float* __restrict__ embed_n,
    float* __restrict__ q_out,
    float* __restrict__ ind_out,
    float* __restrict__ embed_sum,
    float* __restrict__ bins)
{
    int row = blockIdx.x * blockDim.x + threadIdx.x;   // 0..N-1 (grid exact)

    float xr[D];
    {
        const float4* xp = reinterpret_cast<const float4*>(x + (size_t)row * D);
        #pragma unroll
        for (int i = 0; i < D / 4; ++i) {
            float4 t = xp[i];
            xr[4*i+0] = t.x; xr[4*i+1] = t.y; xr[4*i+2] = t.z; xr[4*i+3] = t.w;
        }
    }
    float ss = 0.f;
    #pragma unroll
    for (int i = 0; i < D; ++i) ss = fmaf(xr[i], xr[i], ss);
    float inv = 1.0f / fmaxf(sqrtf(ss), 1e-12f);

    float best = -3.4e38f;
    int   bidx = 0;
    for (int c = 0; c < C; c += 2) {
        const float4* e0 = reinterpret_cast<const float4*>(embed_n + (size_t)c * D);
        const float4* e1 = reinterpret_cast<const float4*>(embed_n + (size_t)(c + 1) * D);
        float a0 = 0.f, a1 = 0.f, a2 = 0.f, a3 = 0.f;
        float b0 = 0.f, b1 = 0.f, b2 = 0.f, b3 = 0.f;
        #pragma unroll
        for (int k = 0; k < D / 4; ++k) {
            float4 ev = e0[k];
            a0 = fmaf(xr[4*k+0], ev.x, a0);
            a1 = fmaf(xr[4*k+1], ev.y, a1);
            a2 = fmaf(xr[4*k+2], ev.z, a2);
            a3 = fmaf(xr[4*k+3], ev.w, a3);
            float4 fv = e1[k];
            b0 = fmaf(xr[4*k+0], fv.x, b0);
            b1 = fmaf(xr[4*k+1], fv.y, b1);
            b2 = fmaf(xr[4*k+2], fv.z, b2);
            b3 = fmaf(xr[4*k+3], fv.w, b3);
        }
        float d0 = (a0 + a1) + (a2 + a3);
        float d1 = (b0 + b1) + (b2 + b3);
        // ascending scan + strict '>' == first-max tie-break (matches argmax)
        if (d0 > best) { best = d0; bidx = c; }
        if (d1 > best) { best = d1; bidx = c + 1; }
    }

    // embed_ind output (stored as float — flat out buffer is read as f32)
    ind_out[row] = (float)bidx;

    // quantize = raw (non-normalized) codebook row gather
    {
        const float4* ep = reinterpret_cast<const float4*>(embed + (size_t)bidx * D);
        float4*       qp = reinterpret_cast<float4*>(q_out + (size_t)row * D);
        #pragma unroll
        for (int i = 0; i < D / 4; ++i) qp[i] = ep[i];
    }

    // EMA statistics: bins and embed_sum (with the normalized row)
    atomicAdd(&bins[bidx], 1.0f);
    #pragma unroll
    for (int k = 0; k < D; ++k)
        atomicAdd(&embed_sum[(size_t)bidx * D + k], xr[k] * inv);
}

// ---------------------------------------------------------------------------
// Kernel 3: EMA finalize per code. One wave per code.
// ---------------------------------------------------------------------------
__global__ __launch_bounds__(256) void finalize_kernel(
    const float* __restrict__ embed,
    const float* __restrict__ cluster_size,
    const float* __restrict__ embed_n,
    const float* __restrict__ embed_sum,
    const float* __restrict__ bins,
    float* __restrict__ new_embed_out,
    float* __restrict__ new_cs_out)
{
    int code = blockIdx.x * 4 + (threadIdx.x >> 6);
    int lane = threadIdx.x & 63;
    float bsum = bins[code];
    if (lane == 0)
        new_cs_out[code] = cluster_size[code] * DECAY + bsum * (1.0f - DECAY);

    float en;
    if (bsum == 0.0f) {               // wave-uniform branch (bsum same per code)
        en = embed_n[code * D + lane];
    } else {
        float v = embed_sum[code * D + lane] / bsum;   // bins_safe == bsum here
        float ss = v * v;
        #pragma unroll
        for (int o = 32; o > 0; o >>= 1) ss += __shfl_xor(ss, o);
        en = v / fmaxf(sqrtf(ss), 1e-12f);
    }
    new_embed_out[code * D + lane] =
        embed[code * D + lane] * DECAY + en * (1.0f - DECAY);
}

// ---------------------------------------------------------------------------
extern "C" void kernel_launch(void* const* d_in, const int* in_sizes, int n_in,
                              void* d_out, int out_size, void* d_ws, size_t ws_size,
                              hipStream_t stream)
{
    const float* x            = (const float*)d_in[0];
    const float* embed        = (const float*)d_in[1];
    const float* cluster_size = (const float*)d_in[2];

    float* out     = (float*)d_out;
    float* q_out   = out;                          // N*D
    float* ind_out = out + (size_t)N * D;          // N
    float* ne_out  = ind_out + N;                  // C*D
    float* ncs_out = ne_out + (size_t)C * D;       // C

    float* ws        = (float*)d_ws;
    float* embed_n   = ws;                         // C*D
    float* embed_sum = embed_n + (size_t)C * D;    // C*D
    float* bins      = embed_sum + (size_t)C * D;  // C

    prep_kernel<<<C / 4, 256, 0, stream>>>(embed, embed_n, embed_sum, bins);
    assign_kernel<<<N / 256, 256, 0, stream>>>(x, embed, embed_n,
                                               q_out, ind_out, embed_sum, bins);
    finalize_kernel<<<C / 4, 256, 0, stream>>>(embed, cluster_size, embed_n,
                                               embed_sum, bins, ne_out, ncs_out);
}

// Round 2
// 1929.801 us; speedup vs baseline: 1.4239x; 1.4239x over previous
//
#include <hip/hip_runtime.h>
#include <math.h>

#define DECAY 0.8f
constexpr int B_    = 16;
constexpr int NSEQ  = 4096;
constexpr int D     = 64;
constexpr int C     = 4096;
constexpr int N     = B_ * NSEQ;   // 65536 rows
constexpr int CHUNKS = 4;          // waves per block, each scans C/CHUNKS codes
constexpr int ROWS_PER_BLOCK = 64;
constexpr int CCHUNK = C / CHUNKS; // 1024

// ---------------------------------------------------------------------------
// Kernel 1: embed_n = l2norm(embed); zero embed_sum and bins.
// ---------------------------------------------------------------------------
__global__ __launch_bounds__(256) void prep_kernel(
    const float* __restrict__ embed,
    float* __restrict__ embed_n,
    float* __restrict__ embed_sum,
    float* __restrict__ bins)
{
    int code = blockIdx.x * 4 + (threadIdx.x >> 6);
    int lane = threadIdx.x & 63;
    float v = embed[code * D + lane];
    float ss = v * v;
    #pragma unroll
    for (int o = 32; o > 0; o >>= 1) ss += __shfl_xor(ss, o);
    float inv = 1.0f / fmaxf(sqrtf(ss), 1e-12f);
    embed_n[code * D + lane]   = v * inv;
    embed_sum[code * D + lane] = 0.0f;
    if (lane == 0) bins[code] = 0.0f;
}

// ---------------------------------------------------------------------------
// Kernel 2: argmax + gather + EMA scatter.
// Block = 256 threads = 4 waves. Wave w scans codes [w*1024,(w+1)*1024) for
// the block's 64 rows (row = blockIdx*64 + lane). embed_n addresses stay
// wave-uniform -> scalar loads. 4x the waves of round 1 (16 waves/CU) to
// hide the scalar-load latency that capped VALUBusy at 17.5%.
// LDS reduction merges chunk results; ascending-chunk strict '>' keeps the
// reference's first-max tie-break (chunk0 holds the lowest indices).
// ---------------------------------------------------------------------------
__global__ __launch_bounds__(256) void assign_kernel(
    const float* __restrict__ x,
    const float* __restrict__ embed,
    const float* __restrict__ embed_n,
    float* __restrict__ q_out,
    float* __restrict__ ind_out,
    float* __restrict__ embed_sum,
    float* __restrict__ bins)
{
    __shared__ float sh_best[CHUNKS][ROWS_PER_BLOCK];
    __shared__ int   sh_idx [CHUNKS][ROWS_PER_BLOCK];

    int r     = threadIdx.x & 63;          // row-in-block == lane
    int chunk = threadIdx.x >> 6;          // wave index
    int row   = blockIdx.x * ROWS_PER_BLOCK + r;

    float xr[D];
    {
        const float4* xp = reinterpret_cast<const float4*>(x + (size_t)row * D);
        #pragma unroll
        for (int i = 0; i < D / 4; ++i) {
            float4 t = xp[i];
            xr[4*i+0] = t.x; xr[4*i+1] = t.y; xr[4*i+2] = t.z; xr[4*i+3] = t.w;
        }
    }
    float ss = 0.f;
    #pragma unroll
    for (int i = 0; i < D; ++i) ss = fmaf(xr[i], xr[i], ss);
    float inv = 1.0f / fmaxf(sqrtf(ss), 1e-12f);

    // ---- scan this wave's code chunk (argmax is scale-invariant in x) ----
    float best = -3.4e38f;
    int   bidx = chunk * CCHUNK;
    for (int c = chunk * CCHUNK; c < (chunk + 1) * CCHUNK; c += 2) {
        const float4* e0 = reinterpret_cast<const float4*>(embed_n + (size_t)c * D);
        const float4* e1 = reinterpret_cast<const float4*>(embed_n + (size_t)(c + 1) * D);
        float a0 = 0.f, a1 = 0.f, a2 = 0.f, a3 = 0.f;
        float b0 = 0.f, b1 = 0.f, b2 = 0.f, b3 = 0.f;
        #pragma unroll
        for (int k = 0; k < D / 4; ++k) {
            float4 ev = e0[k];
            a0 = fmaf(xr[4*k+0], ev.x, a0);
            a1 = fmaf(xr[4*k+1], ev.y, a1);
            a2 = fmaf(xr[4*k+2], ev.z, a2);
            a3 = fmaf(xr[4*k+3], ev.w, a3);
            float4 fv = e1[k];
            b0 = fmaf(xr[4*k+0], fv.x, b0);
            b1 = fmaf(xr[4*k+1], fv.y, b1);
            b2 = fmaf(xr[4*k+2], fv.z, b2);
            b3 = fmaf(xr[4*k+3], fv.w, b3);
        }
        float d0 = (a0 + a1) + (a2 + a3);
        float d1 = (b0 + b1) + (b2 + b3);
        if (d0 > best) { best = d0; bidx = c; }
        if (d1 > best) { best = d1; bidx = c + 1; }
    }

    sh_best[chunk][r] = best;
    sh_idx [chunk][r] = bidx;
    __syncthreads();

    // ---- merge the 4 chunk results (every thread, redundantly) ----
    float fb = -3.4e38f;
    int   fi = 0;
    #pragma unroll
    for (int cc = 0; cc < CHUNKS; ++cc) {
        float v = sh_best[cc][r];
        if (v > fb) { fb = v; fi = sh_idx[cc][r]; }
    }

    if (chunk == 0) {
        ind_out[row] = (float)fi;
        atomicAdd(&bins[fi], 1.0f);
    }

    // quantize gather: 4 chunks each copy 16 floats of the winning raw code
    {
        const float4* ep = reinterpret_cast<const float4*>(embed + (size_t)fi * D) + chunk * 4;
        float4*       qp = reinterpret_cast<float4*>(q_out + (size_t)row * D) + chunk * 4;
        #pragma unroll
        for (int i = 0; i < 4; ++i) qp[i] = ep[i];
    }

    // embed_sum scatter: chunk handles components [16*chunk, 16*chunk+16)
    #pragma unroll
    for (int k = 0; k < 16; ++k) {
        int kk = chunk * 16 + k;
        atomicAdd(&embed_sum[(size_t)fi * D + kk], xr[kk] * inv);
    }
}

// ---------------------------------------------------------------------------
// Kernel 3: EMA finalize per code. One wave per code.
// ---------------------------------------------------------------------------
__global__ __launch_bounds__(256) void finalize_kernel(
    const float* __restrict__ embed,
    const float* __restrict__ cluster_size,
    const float* __restrict__ embed_n,
    const float* __restrict__ embed_sum,
    const float* __restrict__ bins,
    float* __restrict__ new_embed_out,
    float* __restrict__ new_cs_out)
{
    int code = blockIdx.x * 4 + (threadIdx.x >> 6);
    int lane = threadIdx.x & 63;
    float bsum = bins[code];
    if (lane == 0)
        new_cs_out[code] = cluster_size[code] * DECAY + bsum * (1.0f - DECAY);

    float en;
    if (bsum == 0.0f) {               // wave-uniform branch
        en = embed_n[code * D + lane];
    } else {
        float v = embed_sum[code * D + lane] / bsum;
        float ss = v * v;
        #pragma unroll
        for (int o = 32; o > 0; o >>= 1) ss += __shfl_xor(ss, o);
        en = v / fmaxf(sqrtf(ss), 1e-12f);
    }
    new_embed_out[code * D + lane] =
        embed[code * D + lane] * DECAY + en * (1.0f - DECAY);
}

// ---------------------------------------------------------------------------
extern "C" void kernel_launch(void* const* d_in, const int* in_sizes, int n_in,
                              void* d_out, int out_size, void* d_ws, size_t ws_size,
                              hipStream_t stream)
{
    const float* x            = (const float*)d_in[0];
    const float* embed        = (const float*)d_in[1];
    const float* cluster_size = (const float*)d_in[2];

    float* out     = (float*)d_out;
    float* q_out   = out;                          // N*D
    float* ind_out = out + (size_t)N * D;          // N
    float* ne_out  = ind_out + N;                  // C*D
    float* ncs_out = ne_out + (size_t)C * D;       // C

    float* ws        = (float*)d_ws;
    float* embed_n   = ws;                         // C*D
    float* embed_sum = embed_n + (size_t)C * D;    // C*D
    float* bins      = embed_sum + (size_t)C * D;  // C

    prep_kernel<<<C / 4, 256, 0, stream>>>(embed, embed_n, embed_sum, bins);
    assign_kernel<<<N / ROWS_PER_BLOCK, 256, 0, stream>>>(x, embed, embed_n,
                                                          q_out, ind_out,
                                                          embed_sum, bins);
    finalize_kernel<<<C / 4, 256, 0, stream>>>(embed, cluster_size, embed_n,
                                               embed_sum, bins, ne_out, ncs_out);
}

// Round 3
// 747.256 us; speedup vs baseline: 3.6773x; 2.5825x over previous
//
#include <hip/hip_runtime.h>
#include <math.h>

#define DECAY 0.8f
constexpr int B_     = 16;
constexpr int NSEQ   = 4096;
constexpr int D      = 64;
constexpr int C      = 4096;
constexpr int N      = B_ * NSEQ;    // 65536 rows
constexpr int NCHUNK = 8;            // code-dim split across blockIdx.y
constexpr int CCHUNK = C / NCHUNK;   // 512 codes per chunk

// ---------------------------------------------------------------------------
// Kernel 1: embed_n = l2norm(embed); zero embed_sum and bins.
// ---------------------------------------------------------------------------
__global__ __launch_bounds__(256) void prep_kernel(
    const float* __restrict__ embed,
    float* __restrict__ embed_n,
    float* __restrict__ embed_sum,
    float* __restrict__ bins)
{
    int code = blockIdx.x * 4 + (threadIdx.x >> 6);
    int lane = threadIdx.x & 63;
    float v = embed[code * D + lane];
    float ss = v * v;
    #pragma unroll
    for (int o = 32; o > 0; o >>= 1) ss += __shfl_xor(ss, o);
    float inv = 1.0f / fmaxf(sqrtf(ss), 1e-12f);
    embed_n[code * D + lane]   = v * inv;
    embed_sum[code * D + lane] = 0.0f;
    if (lane == 0) bins[code] = 0.0f;
}

// ---------------------------------------------------------------------------
// Kernel 2: partial argmax. One thread per row; blockIdx.y selects the code
// chunk, so loop bounds are SGPR-uniform -> compiler emits s_load for the
// codebook (round-1 mix: v_fmac with SGPR operand, zero codebook VMEM).
// 2048 blocks = 8192 waves (vs round-1's 1024) to hide s_load latency.
// Partial (best, idx) written into the row's own quantize slot in d_out
// (floats 2*chunk .. 2*chunk+1 of the 64-float slot) — overwritten by the
// merge kernel, so no residual state and no extra ws.
// ---------------------------------------------------------------------------
__global__ __launch_bounds__(256) void assign_partial_kernel(
    const float* __restrict__ x,
    const float* __restrict__ embed_n,
    float* __restrict__ part)            // == q_out region of d_out
{
    int row   = blockIdx.x * 256 + threadIdx.x;
    int cbase = blockIdx.y * CCHUNK;     // uniform (SGPR)

    float xr[D];
    {
        const float4* xp = reinterpret_cast<const float4*>(x + (size_t)row * D);
        #pragma unroll
        for (int i = 0; i < D / 4; ++i) {
            float4 t = xp[i];
            xr[4*i+0] = t.x; xr[4*i+1] = t.y; xr[4*i+2] = t.z; xr[4*i+3] = t.w;
        }
    }

    float best = -3.4e38f;
    int   bidx = cbase;
    for (int c = cbase; c < cbase + CCHUNK; c += 2) {
        const float4* e0 = reinterpret_cast<const float4*>(embed_n + (size_t)c * D);
        const float4* e1 = reinterpret_cast<const float4*>(embed_n + (size_t)(c + 1) * D);
        float a0 = 0.f, a1 = 0.f, a2 = 0.f, a3 = 0.f;
        float b0 = 0.f, b1 = 0.f, b2 = 0.f, b3 = 0.f;
        #pragma unroll
        for (int k = 0; k < D / 4; ++k) {
            float4 ev = e0[k];
            a0 = fmaf(xr[4*k+0], ev.x, a0);
            a1 = fmaf(xr[4*k+1], ev.y, a1);
            a2 = fmaf(xr[4*k+2], ev.z, a2);
            a3 = fmaf(xr[4*k+3], ev.w, a3);
            float4 fv = e1[k];
            b0 = fmaf(xr[4*k+0], fv.x, b0);
            b1 = fmaf(xr[4*k+1], fv.y, b1);
            b2 = fmaf(xr[4*k+2], fv.z, b2);
            b3 = fmaf(xr[4*k+3], fv.w, b3);
        }
        float d0 = (a0 + a1) + (a2 + a3);
        float d1 = (b0 + b1) + (b2 + b3);
        if (d0 > best) { best = d0; bidx = c; }
        if (d1 > best) { best = d1; bidx = c + 1; }
    }

    float2 p;
    p.x = best;
    p.y = (float)bidx;                   // idx < 4096: exactly representable
    *reinterpret_cast<float2*>(part + (size_t)row * D + blockIdx.y * 2) = p;
}

// ---------------------------------------------------------------------------
// Kernel 3: merge partials + quantize gather + EMA scatters.
// One thread per row. Reads its 8 (best,idx) pairs from the quantize slot
// FIRST, then overwrites the slot with the gathered raw codebook row.
// Ascending-chunk strict '>' keeps the reference first-max tie-break.
// ---------------------------------------------------------------------------
__global__ __launch_bounds__(256) void merge_kernel(
    const float* __restrict__ x,
    const float* __restrict__ embed,
    float* __restrict__ q_out,
    float* __restrict__ ind_out,
    float* __restrict__ embed_sum,
    float* __restrict__ bins)
{
    int row = blockIdx.x * 256 + threadIdx.x;

    // read partials (4 x float4 = 8 pairs)
    float fb = -3.4e38f;
    int   fi = 0;
    {
        const float4* pp = reinterpret_cast<const float4*>(q_out + (size_t)row * D);
        #pragma unroll
        for (int i = 0; i < NCHUNK / 2; ++i) {
            float4 t = pp[i];
            if (t.x > fb) { fb = t.x; fi = (int)t.y; }
            if (t.z > fb) { fb = t.z; fi = (int)t.w; }
        }
    }

    ind_out[row] = (float)fi;
    atomicAdd(&bins[fi], 1.0f);

    // reload x row for the normalized accumulation
    float xr[D];
    {
        const float4* xp = reinterpret_cast<const float4*>(x + (size_t)row * D);
        #pragma unroll
        for (int i = 0; i < D / 4; ++i) {
            float4 t = xp[i];
            xr[4*i+0] = t.x; xr[4*i+1] = t.y; xr[4*i+2] = t.z; xr[4*i+3] = t.w;
        }
    }
    float ss = 0.f;
    #pragma unroll
    for (int i = 0; i < D; ++i) ss = fmaf(xr[i], xr[i], ss);
    float inv = 1.0f / fmaxf(sqrtf(ss), 1e-12f);

    // quantize = raw codebook row gather (overwrites the partials)
    {
        const float4* ep = reinterpret_cast<const float4*>(embed + (size_t)fi * D);
        float4*       qp = reinterpret_cast<float4*>(q_out + (size_t)row * D);
        #pragma unroll
        for (int i = 0; i < D / 4; ++i) qp[i] = ep[i];
    }

    #pragma unroll
    for (int k = 0; k < D; ++k)
        atomicAdd(&embed_sum[(size_t)fi * D + k], xr[k] * inv);
}

// ---------------------------------------------------------------------------
// Kernel 4: EMA finalize per code. One wave per code.
// ---------------------------------------------------------------------------
__global__ __launch_bounds__(256) void finalize_kernel(
    const float* __restrict__ embed,
    const float* __restrict__ cluster_size,
    const float* __restrict__ embed_n,
    const float* __restrict__ embed_sum,
    const float* __restrict__ bins,
    float* __restrict__ new_embed_out,
    float* __restrict__ new_cs_out)
{
    int code = blockIdx.x * 4 + (threadIdx.x >> 6);
    int lane = threadIdx.x & 63;
    float bsum = bins[code];
    if (lane == 0)
        new_cs_out[code] = cluster_size[code] * DECAY + bsum * (1.0f - DECAY);

    float en;
    if (bsum == 0.0f) {               // wave-uniform branch
        en = embed_n[code * D + lane];
    } else {
        float v = embed_sum[code * D + lane] / bsum;
        float ss = v * v;
        #pragma unroll
        for (int o = 32; o > 0; o >>= 1) ss += __shfl_xor(ss, o);
        en = v / fmaxf(sqrtf(ss), 1e-12f);
    }
    new_embed_out[code * D + lane] =
        embed[code * D + lane] * DECAY + en * (1.0f - DECAY);
}

// ---------------------------------------------------------------------------
extern "C" void kernel_launch(void* const* d_in, const int* in_sizes, int n_in,
                              void* d_out, int out_size, void* d_ws, size_t ws_size,
                              hipStream_t stream)
{
    const float* x            = (const float*)d_in[0];
    const float* embed        = (const float*)d_in[1];
    const float* cluster_size = (const float*)d_in[2];

    float* out     = (float*)d_out;
    float* q_out   = out;                          // N*D
    float* ind_out = out + (size_t)N * D;          // N
    float* ne_out  = ind_out + N;                  // C*D
    float* ncs_out = ne_out + (size_t)C * D;       // C

    float* ws        = (float*)d_ws;
    float* embed_n   = ws;                         // C*D
    float* embed_sum = embed_n + (size_t)C * D;    // C*D
    float* bins      = embed_sum + (size_t)C * D;  // C

    prep_kernel<<<C / 4, 256, 0, stream>>>(embed, embed_n, embed_sum, bins);
    assign_partial_kernel<<<dim3(N / 256, NCHUNK), 256, 0, stream>>>(
        x, embed_n, q_out);
    merge_kernel<<<N / 256, 256, 0, stream>>>(x, embed, q_out, ind_out,
                                              embed_sum, bins);
    finalize_kernel<<<C / 4, 256, 0, stream>>>(embed, cluster_size, embed_n,
                                               embed_sum, bins, ne_out, ncs_out);
}

// Round 4
// 224.577 us; speedup vs baseline: 12.2359x; 3.3274x over previous
//
#include <hip/hip_runtime.h>
#include <math.h>

#define DECAY 0.8f
constexpr int B_   = 16;
constexpr int NSEQ = 4096;
constexpr int D    = 64;
constexpr int C    = 4096;
constexpr int N    = B_ * NSEQ;      // 65536 rows

typedef __attribute__((ext_vector_type(8))) short bf16x8;
typedef __attribute__((ext_vector_type(4))) float f32x4;

__device__ __forceinline__ unsigned short bf16_rn(float f) {
    unsigned u = __builtin_bit_cast(unsigned, f);
    u += 0x7FFFu + ((u >> 16) & 1u);
    return (unsigned short)(u >> 16);
}
__device__ __forceinline__ float bf16_to_f(unsigned short h) {
    unsigned u = ((unsigned)h) << 16;
    return __builtin_bit_cast(float, u);
}
__device__ __forceinline__ f32x4 mfma16(bf16x8 a, bf16x8 b, f32x4 c) {
    return __builtin_amdgcn_mfma_f32_16x16x32_bf16(a, b, c, 0, 0, 0);
}

// ---------------------------------------------------------------------------
// Kernel 1: embed_n = l2norm(embed) (f32, for fallback+finalize), plus bf16
// hi/lo split written in the XOR-swizzled LDS-image layout (granule g of code
// row stored at g^(code&7)) so the assign kernel stages with a LINEAR copy
// and reads conflict-free (G4/T2, rule 21c: bake inverse swizzle into source).
// Also zeroes embed_sum / bins / dirty_count.
// ---------------------------------------------------------------------------
__global__ __launch_bounds__(256) void prep_e_kernel(
    const float* __restrict__ embed,
    float* __restrict__ embed_n,
    unsigned short* __restrict__ e_hi,
    unsigned short* __restrict__ e_lo,
    float* __restrict__ embed_sum,
    float* __restrict__ bins,
    int* __restrict__ dirty_count)
{
    int code = blockIdx.x * 4 + (threadIdx.x >> 6);
    int lane = threadIdx.x & 63;
    float v = embed[code * D + lane];
    float ss = v * v;
    #pragma unroll
    for (int o = 32; o > 0; o >>= 1) ss += __shfl_xor(ss, o);
    float inv = 1.0f / fmaxf(sqrtf(ss), 1e-12f);
    float en = v * inv;
    embed_n[code * D + lane] = en;

    unsigned short hi = bf16_rn(en);
    unsigned short lo = bf16_rn(en - bf16_to_f(hi));
    int g   = lane >> 3;                               // 16B granule 0..7
    int pos = code * D + ((g ^ (code & 7)) << 3) + (lane & 7);
    e_hi[pos] = hi;
    e_lo[pos] = lo;

    embed_sum[code * D + lane] = 0.0f;
    if (lane == 0) bins[code] = 0.0f;
    if (blockIdx.x == 0 && threadIdx.x == 0) *dirty_count = 0;
}

// ---------------------------------------------------------------------------
// Kernel 2: MFMA argmax. dist[code][row] = e_hi·x_hi + e_lo·x_hi + e_hi·x_lo
// (bf16 split, fp32 accum; lo·lo dropped, |err| <~ 1.2e-5 * ||x||).
// Wave = 32 x-rows (2 row-groups of 16). A-operand = 16 codes (frag: lane
// m-index = l&15, k = (l>>4)*8+j), B-operand = 16 x-rows, same lane mapping.
// D: col = lane&15 = x-row, row = (lane>>4)*4+reg = code  [measured m89].
// Codebook staged per 256-code panel in LDS (64 KB), linear copy of the
// pre-swizzled global image; reads XOR back -> 2 lanes/bank-group (free).
// Per (lane,row-group,reg) slot keeps running top-2 (m1,i1,m2); slots merged
// at the end with (value desc, index asc) total order == reference argmax
// first-max tie-break. Rows with m1-m2 <= 1e-4*||x|| go to the dirty list.
// ---------------------------------------------------------------------------
__global__ __launch_bounds__(256) void assign_mfma_kernel(
    const float* __restrict__ x,
    const unsigned short* __restrict__ e_hi,
    const unsigned short* __restrict__ e_lo,
    float* __restrict__ ind_out,
    int* __restrict__ dirty_count,
    int* __restrict__ dirty_list)
{
    __shared__ unsigned short lds_hi[256 * D];   // 32 KB
    __shared__ unsigned short lds_lo[256 * D];   // 32 KB

    const int tid  = threadIdx.x;
    const int lane = tid & 63;
    const int wid  = tid >> 6;
    const int l15  = lane & 15;
    const int lg   = lane >> 4;                  // 0..3
    const int rb   = (blockIdx.x * 4 + wid) * 32;

    // ---- load x fragments (2 row-groups x 2 K-chunks), split to bf16 hi/lo
    bf16x8 xhi[2][2], xlo[2][2];
    float  ssr[2];
    #pragma unroll
    for (int g = 0; g < 2; ++g) {
        float ssp = 0.0f;
        #pragma unroll
        for (int c = 0; c < 2; ++c) {
            const float* p = x + (size_t)(rb + g * 16 + l15) * D + c * 32 + lg * 8;
            float4 t0 = *(const float4*)p;
            float4 t1 = *(const float4*)(p + 4);
            float e[8] = {t0.x, t0.y, t0.z, t0.w, t1.x, t1.y, t1.z, t1.w};
            bf16x8 h, l2;
            #pragma unroll
            for (int j = 0; j < 8; ++j) {
                ssp = fmaf(e[j], e[j], ssp);
                unsigned short hh = bf16_rn(e[j]);
                h[j]  = (short)hh;
                l2[j] = (short)bf16_rn(e[j] - bf16_to_f(hh));
            }
            xhi[g][c] = h;
            xlo[g][c] = l2;
        }
        ssp += __shfl_xor(ssp, 16);
        ssp += __shfl_xor(ssp, 32);
        ssr[g] = ssp;                            // ||x_row||^2, full
    }

    // swizzled LDS read offsets (elems); code&7 == l15&7 is tile-invariant
    const int s7   = l15 & 7;
    const int off0 = l15 * D + (((0 * 4 + lg) ^ s7) << 3);   // chunk c=0
    const int off1 = l15 * D + (((1 * 4 + lg) ^ s7) << 3);   // chunk c=1

    float m1[2][4], m2[2][4];
    int   i1[2][4];
    #pragma unroll
    for (int g = 0; g < 2; ++g)
        #pragma unroll
        for (int r = 0; r < 4; ++r) {
            m1[g][r] = -3.4e38f; m2[g][r] = -3.4e38f; i1[g][r] = 0;
        }

    for (int p = 0; p < 16; ++p) {               // 16 panels of 256 codes
        __syncthreads();
        {   // linear stage: 64 KB, 256 thr x 16B x 8 iters per half
            const float4* gh = (const float4*)(e_hi + p * 256 * D);
            const float4* gl = (const float4*)(e_lo + p * 256 * D);
            float4* lh = (float4*)lds_hi;
            float4* ll = (float4*)lds_lo;
            #pragma unroll
            for (int i = 0; i < 8; ++i) {
                lh[i * 256 + tid] = gh[i * 256 + tid];
                ll[i * 256 + tid] = gl[i * 256 + tid];
            }
        }
        __syncthreads();

        for (int t = 0; t < 16; ++t) {           // 16 code-tiles of 16
            bf16x8 eh0 = *(const bf16x8*)(lds_hi + t * 1024 + off0);
            bf16x8 eh1 = *(const bf16x8*)(lds_hi + t * 1024 + off1);
            bf16x8 el0 = *(const bf16x8*)(lds_lo + t * 1024 + off0);
            bf16x8 el1 = *(const bf16x8*)(lds_lo + t * 1024 + off1);
            int cbase = p * 256 + t * 16 + lg * 4;
            #pragma unroll
            for (int g = 0; g < 2; ++g) {
                f32x4 acc = {0.f, 0.f, 0.f, 0.f};
                acc = mfma16(eh0, xhi[g][0], acc);
                acc = mfma16(eh1, xhi[g][1], acc);
                acc = mfma16(el0, xhi[g][0], acc);
                acc = mfma16(el1, xhi[g][1], acc);
                acc = mfma16(eh0, xlo[g][0], acc);
                acc = mfma16(eh1, xlo[g][1], acc);
                #pragma unroll
                for (int r = 0; r < 4; ++r) {
                    float v  = acc[r];
                    bool  gt = v > m1[g][r];
                    float mx = fmaxf(m2[g][r], v);
                    m2[g][r] = gt ? m1[g][r] : mx;
                    i1[g][r] = gt ? (cbase + r) : i1[g][r];
                    m1[g][r] = gt ? v : m1[g][r];
                }
            }
        }
    }

    // ---- merge 16 slots per row -> final (m1,i1,m2); write ind + dirty flag
    #pragma unroll
    for (int g = 0; g < 2; ++g) {
        float a1 = m1[g][0], a2 = m2[g][0];
        int   ai = i1[g][0];
        #pragma unroll
        for (int r = 1; r < 4; ++r) {            // ascending reg = ascending code
            float b1 = m1[g][r], b2 = m2[g][r];
            int   bi = i1[g][r];
            float nm2 = fmaxf(fminf(a1, b1), fmaxf(a2, b2));
            bool  take = (b1 > a1);
            a1 = take ? b1 : a1;
            ai = take ? bi : ai;
            a2 = nm2;
        }
        #pragma unroll
        for (int d = 16; d <= 32; d <<= 1) {
            float b1 = __shfl_xor(a1, d);
            float b2 = __shfl_xor(a2, d);
            int   bi = __shfl_xor(ai, d);
            float nm2 = fmaxf(fminf(a1, b1), fmaxf(a2, b2));
            bool  take = (b1 > a1) || (b1 == a1 && bi < ai);
            a1 = take ? b1 : a1;
            ai = take ? bi : ai;
            a2 = nm2;
        }
        if (lane < 16) {
            int row = rb + g * 16 + lane;
            ind_out[row] = (float)ai;
            if (a1 - a2 <= 1e-4f * sqrtf(ssr[g])) {
                int slot = atomicAdd(dirty_count, 1);
                dirty_list[slot] = row;
            }
        }
    }
}

// ---------------------------------------------------------------------------
// Kernel 3: exact fp32 re-argmax for dirty rows (near-ties). One block per
// dirty row (grid-stride); thread t scans codes [16t,16t+16) ascending;
// block reduce ascending => reference first-max tie-break.
// ---------------------------------------------------------------------------
__global__ __launch_bounds__(256) void fallback_kernel(
    const float* __restrict__ x,
    const float* __restrict__ embed_n,
    const int* __restrict__ dirty_count,
    const int* __restrict__ dirty_list,
    float* __restrict__ ind_out)
{
    __shared__ float xs[D];
    __shared__ float bv[256];
    __shared__ int   bidx[256];
    int cnt = *dirty_count;
    for (int i = blockIdx.x; i < cnt; i += gridDim.x) {
        int row = dirty_list[i];
        __syncthreads();
        if (threadIdx.x < D) xs[threadIdx.x] = x[(size_t)row * D + threadIdx.x];
        __syncthreads();
        float best = -3.4e38f;
        int   bi   = 0;
        int   c0   = threadIdx.x * 16;
        for (int c = c0; c < c0 + 16; ++c) {
            const float4* ep = (const float4*)(embed_n + (size_t)c * D);
            const float4* xp = (const float4*)xs;
            float a0 = 0.f, a1 = 0.f, a2 = 0.f, a3 = 0.f;
            #pragma unroll
            for (int k = 0; k < D / 4; ++k) {
                float4 e = ep[k], xx = xp[k];
                a0 = fmaf(e.x, xx.x, a0);
                a1 = fmaf(e.y, xx.y, a1);
                a2 = fmaf(e.z, xx.z, a2);
                a3 = fmaf(e.w, xx.w, a3);
            }
            float dd = (a0 + a1) + (a2 + a3);
            if (dd > best) { best = dd; bi = c; }
        }
        bv[threadIdx.x]   = best;
        bidx[threadIdx.x] = bi;
        __syncthreads();
        if (threadIdx.x == 0) {
            float fb = -3.4e38f; int fi = 0;
            for (int t = 0; t < 256; ++t)
                if (bv[t] > fb) { fb = bv[t]; fi = bidx[t]; }
            ind_out[row] = (float)fi;
        }
    }
}

// ---------------------------------------------------------------------------
// Kernel 4: scatter epilogue, one WAVE per row: coalesced quantize gather,
// one atomic per lane for embed_sum (contiguous 256B burst per row), one
// bins atomic per row.
// ---------------------------------------------------------------------------
__global__ __launch_bounds__(256) void scatter_kernel(
    const float* __restrict__ x,
    const float* __restrict__ embed,
    const float* __restrict__ ind_out,
    float* __restrict__ q_out,
    float* __restrict__ embed_sum,
    float* __restrict__ bins)
{
    int wid  = threadIdx.x >> 6;
    int lane = threadIdx.x & 63;
    int row  = blockIdx.x * 4 + wid;
    int fi   = (int)ind_out[row];
    float xk = x[(size_t)row * D + lane];
    float ss = xk * xk;
    #pragma unroll
    for (int o = 32; o > 0; o >>= 1) ss += __shfl_xor(ss, o);
    float inv = 1.0f / fmaxf(sqrtf(ss), 1e-12f);
    q_out[(size_t)row * D + lane] = embed[(size_t)fi * D + lane];
    atomicAdd(&embed_sum[(size_t)fi * D + lane], xk * inv);
    if (lane == 0) atomicAdd(&bins[fi], 1.0f);
}

// ---------------------------------------------------------------------------
// Kernel 5: EMA finalize per code. One wave per code.
// ---------------------------------------------------------------------------
__global__ __launch_bounds__(256) void finalize_kernel(
    const float* __restrict__ embed,
    const float* __restrict__ cluster_size,
    const float* __restrict__ embed_n,
    const float* __restrict__ embed_sum,
    const float* __restrict__ bins,
    float* __restrict__ new_embed_out,
    float* __restrict__ new_cs_out)
{
    int code = blockIdx.x * 4 + (threadIdx.x >> 6);
    int lane = threadIdx.x & 63;
    float bsum = bins[code];
    if (lane == 0)
        new_cs_out[code] = cluster_size[code] * DECAY + bsum * (1.0f - DECAY);

    float en;
    if (bsum == 0.0f) {
        en = embed_n[code * D + lane];
    } else {
        float v = embed_sum[code * D + lane] / bsum;
        float ss = v * v;
        #pragma unroll
        for (int o = 32; o > 0; o >>= 1) ss += __shfl_xor(ss, o);
        en = v / fmaxf(sqrtf(ss), 1e-12f);
    }
    new_embed_out[code * D + lane] =
        embed[code * D + lane] * DECAY + en * (1.0f - DECAY);
}

// ---------------------------------------------------------------------------
extern "C" void kernel_launch(void* const* d_in, const int* in_sizes, int n_in,
                              void* d_out, int out_size, void* d_ws, size_t ws_size,
                              hipStream_t stream)
{
    const float* x            = (const float*)d_in[0];
    const float* embed        = (const float*)d_in[1];
    const float* cluster_size = (const float*)d_in[2];

    float* out     = (float*)d_out;
    float* q_out   = out;                          // N*D
    float* ind_out = out + (size_t)N * D;          // N
    float* ne_out  = ind_out + N;                  // C*D
    float* ncs_out = ne_out + (size_t)C * D;       // C

    char* ws = (char*)d_ws;
    float*          embed_n     = (float*)ws;                       // 1 MB
    float*          embed_sum   = (float*)(ws + (1u << 20));        // 1 MB
    float*          bins        = (float*)(ws + (2u << 20));        // 16 KB
    int*            dirty_list  = (int*)(ws + (2u << 20) + 65536);  // 256 KB
    int*            dirty_count = (int*)(ws + (2u << 20) + 65536 + 262144);
    unsigned short* e_hi        = (unsigned short*)(ws + 3 * (1u << 20));  // 512 KB
    unsigned short* e_lo        = (unsigned short*)(ws + 3 * (1u << 20) + 524288);

    prep_e_kernel<<<C / 4, 256, 0, stream>>>(embed, embed_n, e_hi, e_lo,
                                             embed_sum, bins, dirty_count);
    assign_mfma_kernel<<<N / 128, 256, 0, stream>>>(x, e_hi, e_lo, ind_out,
                                                    dirty_count, dirty_list);
    fallback_kernel<<<256, 256, 0, stream>>>(x, embed_n, dirty_count,
                                             dirty_list, ind_out);
    scatter_kernel<<<N / 4, 256, 0, stream>>>(x, embed, ind_out, q_out,
                                              embed_sum, bins);
    finalize_kernel<<<C / 4, 256, 0, stream>>>(embed, cluster_size, embed_n,
                                               embed_sum, bins, ne_out, ncs_out);
}